// Round 3
// baseline (437.262 us; speedup 1.0000x reference)
//
#include <hip/hip_runtime.h>

namespace {

typedef __attribute__((ext_vector_type(8)))  short          short8;
typedef __attribute__((ext_vector_type(8)))  unsigned short u16x8;
typedef __attribute__((ext_vector_type(4)))  unsigned short u16x4;
typedef __attribute__((ext_vector_type(4)))  float          f32x4;

constexpr int V   = 200;
constexpr int VP  = 208;   // v padded (13 x 16)
constexpr int UP  = 224;   // u padded (7 x 32)
constexpr int F   = 64;
constexpr int FO  = 64;
constexpr int NT  = 512;   // N*T

// ---- ws layout (bytes) ----
constexpr size_t WS_SMIN  = 0;                         // ushort [512][208][224] = 47,710,208
constexpr size_t WS_C     = 47710208;                  // float  [512][208]     =    425,984
constexpr size_t WS_ATTT  = 48136192;                  // float  [8][224][224]  =  1,605,632
constexpr size_t WS_ADIAG = 49741824;                  // float  [8][224]       =      7,168

__device__ __forceinline__ unsigned short f2bf(float x) {
    union { float f; unsigned u; } c; c.f = x;
    unsigned r = c.u + 0x7FFF + ((c.u >> 16) & 1);
    return (unsigned short)(r >> 16);
}
__device__ __forceinline__ float bf2f(unsigned short h) {
    union { unsigned u; float f; } c; c.u = ((unsigned)h) << 16;
    return c.f;
}
__device__ __forceinline__ void fma4(float4& o, float s, const float4& t) {
    o.x += s * t.x; o.y += s * t.y; o.z += s * t.z; o.w += s * t.w;
}

// ============ P1: S_min (bf16, padded) + c[v] = d[v]-1-S[v][v] ============
// grid (512, 7): block b, 32-row band i. S read 2x (row stripe + col stripe),
// both staged through LDS so global reads stay coalesced.
__global__ __launch_bounds__(256)
void prep_smin(const float* __restrict__ S,
               unsigned short* __restrict__ smin,
               float* __restrict__ c_ws)
{
    __shared__ float rowbuf[32][204];   // S[band rows][0..200) , then m (in-place)
    __shared__ float colbuf[200][36];   // S[all rows][band cols]
    __shared__ float dpart[32][8];

    const int b    = blockIdx.x;
    const int band = blockIdx.y;
    const int tid  = threadIdx.x;
    const float* __restrict__ Sp = S + (size_t)b * (V * V);

    // stage row stripe: S[32band + r][j], coalesced float4
    for (int idx = tid; idx < 32 * 50; idx += 256) {
        const int r = idx / 50, ch = idx % 50;
        const int rg = band * 32 + r;
        float4 v = make_float4(0.f, 0.f, 0.f, 0.f);
        if (rg < V) v = *(const float4*)&Sp[rg * V + 4 * ch];
        rowbuf[r][4 * ch + 0] = v.x; rowbuf[r][4 * ch + 1] = v.y;
        rowbuf[r][4 * ch + 2] = v.z; rowbuf[r][4 * ch + 3] = v.w;
    }
    // stage col stripe: S[j][32band + 4ch .. +3], coalesced float4
    for (int idx = tid; idx < 200 * 8; idx += 256) {
        const int j = idx >> 3, ch = idx & 7;
        float4 v = make_float4(0.f, 0.f, 0.f, 0.f);
        if (8 * band + ch <= 49)   // cols fully < 200
            v = *(const float4*)&Sp[j * V + band * 32 + 4 * ch];
        colbuf[j][4 * ch + 0] = v.x; colbuf[j][4 * ch + 1] = v.y;
        colbuf[j][4 * ch + 2] = v.z; colbuf[j][4 * ch + 3] = v.w;
    }
    __syncthreads();

    // compute m = min(S[rg][j], S[j][rg]) in-place into rowbuf; partial d
    const int r = tid >> 3, cseg = tid & 7;
    float dp = 0.f;
    for (int jj = 0; jj < 28; ++jj) {
        const int j = 28 * cseg + jj;
        if (j < V) {
            const float m = fminf(rowbuf[r][j], colbuf[j][r]);
            rowbuf[r][j] = m;
            dp += m;
        }
    }
    dpart[r][cseg] = dp;
    __syncthreads();

    // c[v] (exact fp32 d and diag)
    if (tid < 32) {
        const int vg = band * 32 + tid;
        if (vg < VP) {
            float cv = 0.f;
            if (vg < V) {
                float d = 0.f;
                #pragma unroll
                for (int cc = 0; cc < 8; ++cc) d += dpart[tid][cc];
                cv = d - 1.0f - rowbuf[tid][vg];
            }
            c_ws[b * VP + vg] = cv;
        }
    }

    // writeout bf16, padded to 224 cols / 208 rows
    for (int idx = tid; idx < 32 * 28; idx += 256) {
        const int rr = idx / 28, ch = idx % 28;
        const int vg = band * 32 + rr;
        if (vg < VP) {
            u16x8 o;
            #pragma unroll
            for (int jj = 0; jj < 8; ++jj) {
                const int j = 8 * ch + jj;
                o[jj] = (j < V) ? f2bf(rowbuf[rr][j]) : (unsigned short)0;
            }
            *(u16x8*)&smin[(size_t)b * (VP * UP) + vg * UP + 8 * ch] = o;
        }
    }
}

// ============ P2: AttT[n][v][u] = Att[n][u][v] (fp32, zero-padded) + diag ====
// grid (8, 49): 32x32 tile transpose through LDS.
__global__ __launch_bounds__(256)
void prep_att(const float* __restrict__ Att,
              float* __restrict__ attT,
              float* __restrict__ adiag)
{
    __shared__ float T[32][33];
    const int n  = blockIdx.x;
    const int ut = blockIdx.y / 7, vt = blockIdx.y % 7;
    const int tid = threadIdx.x;

    for (int idx = tid; idx < 1024; idx += 256) {
        const int rr = idx >> 5, cc = idx & 31;
        const int u = 32 * ut + rr, v = 32 * vt + cc;
        T[rr][cc] = (u < V && v < V) ? Att[(size_t)n * (V * V) + u * V + v] : 0.f;
    }
    __syncthreads();
    for (int idx = tid; idx < 1024; idx += 256) {
        const int r2 = idx >> 5, c2 = idx & 31;       // r2: v-local, c2: u-local
        attT[(size_t)n * (UP * UP) + (32 * vt + r2) * UP + 32 * ut + c2] = T[c2][r2];
    }
    if (ut == vt && tid < 32)
        adiag[n * UP + 32 * vt + tid] = T[tid][tid];
}

// ============ G: MFMA main loop (OFF-DIAGONAL only, bf16) + fp32 diag +
// fp32 VALU Theta epilogue. One block per (n,t). ============
constexpr int XS_S = 68;   // xs stride (bf16 elems)
constexpr int A_S  = 40;   // A-tile stride (bf16 elems)
constexpr int YS_S = 68;   // ys stride (f32)

__global__ __launch_bounds__(256, 2)
void cheb_main(const float* __restrict__ x,
               const float* __restrict__ Theta,
               const unsigned short* __restrict__ smin,
               const float* __restrict__ c_ws,
               const float* __restrict__ attT,
               const float* __restrict__ adiag,
               float* __restrict__ out)
{
    __shared__ __align__(16) char smem[65408];
    unsigned short* xs = (unsigned short*)smem;                    // 30,464 B
    unsigned short* A1 = (unsigned short*)(smem + 30464);          // 16,640 B
    unsigned short* A2 = (unsigned short*)(smem + 47104);          // 16,640 B
    float*          ys = (float*)smem;                             // 56,576 B (epilogue)
    float*        cbuf = (float*)(smem + 63744);                   //    832 B
    float*       adbuf = (float*)(smem + 64576);                   //    832 B

    const int tid = threadIdx.x;
    const int b   = blockIdx.x;
    const int n   = b >> 6;
    const float* __restrict__ xp = x + (size_t)b * (V * F);
    const unsigned short* __restrict__ sm = smin + (size_t)b * (VP * UP);
    const float* __restrict__ atp = attT + (size_t)n * (UP * UP);
    float* __restrict__ op = out + (size_t)b * (V * FO);

    // ---- stage x -> bf16 xs[u][f] (zeros for u >= 200) ----
    for (int idx = tid; idx < UP * 16; idx += 256) {
        const int u = idx >> 4, fg = idx & 15;
        u16x4 w; w[0] = 0; w[1] = 0; w[2] = 0; w[3] = 0;
        if (u < V) {
            const float4 v = *(const float4*)&xp[u * F + 4 * fg];
            w[0] = f2bf(v.x); w[1] = f2bf(v.y); w[2] = f2bf(v.z); w[3] = f2bf(v.w);
        }
        *(u16x4*)&xs[u * XS_S + 4 * fg] = w;
    }
    if (tid < VP) {
        cbuf[tid]  = c_ws[b * VP + tid];
        adbuf[tid] = adiag[n * UP + tid];
    }

    const int wave = tid >> 6, lane = tid & 63;
    const int q = lane >> 4, ln = lane & 15;
    const int vbase[4] = {0, 4, 7, 10};
    const int vcnt[4]  = {4, 3, 3, 3};
    const int myBase = vbase[wave], myCnt = vcnt[wave];

    f32x4 acc1[4][4], acc2[4][4];
    #pragma unroll
    for (int i = 0; i < 4; ++i)
        #pragma unroll
        for (int j = 0; j < 4; ++j) {
            acc1[i][j] = (f32x4)0.f; acc2[i][j] = (f32x4)0.f;
        }

    // ---- K loop: 7 steps of 32 u's; diagonal (u==v) EXCLUDED from bf16 path ----
    for (int kt = 0; kt < 7; ++kt) {
        const int u0 = 32 * kt;
        __syncthreads();   // A tiles from prev step consumed; xs/cbuf ready (kt=0)
        // build A1/A2 bf16 coefficient tiles [208 v][32 u], zero on diagonal
        for (int idx = tid; idx < VP * 4; idx += 256) {
            const int v = idx >> 2, ch = idx & 3;
            const int u8 = u0 + 8 * ch;
            const u16x8 s8 = *(const u16x8*)&sm[v * UP + u8];
            const float4 a0 = *(const float4*)&atp[v * UP + u8];
            const float4 a1 = *(const float4*)&atp[v * UP + u8 + 4];
            float att[8] = {a0.x, a0.y, a0.z, a0.w, a1.x, a1.y, a1.z, a1.w};
            u16x8 w1, w2;
            #pragma unroll
            for (int jj = 0; jj < 8; ++jj) {
                const float m = bf2f(s8[jj]);
                if (u8 + jj == v) {        // diagonal handled in fp32 epilogue
                    w1[jj] = 0; w2[jj] = 0;
                } else {
                    w1[jj] = f2bf(-m * att[jj]);
                    w2[jj] = f2bf(2.0f * m * m * att[jj]);
                }
            }
            *(u16x8*)&A1[v * A_S + 8 * ch] = w1;
            *(u16x8*)&A2[v * A_S + 8 * ch] = w2;
        }
        __syncthreads();
        // B fragments from xs (shared across vt and both polys)
        short8 bfr[4];
        #pragma unroll
        for (int ft = 0; ft < 4; ++ft)
            #pragma unroll
            for (int j = 0; j < 8; ++j)
                bfr[ft][j] = (short)xs[(u0 + 8 * q + j) * XS_S + 16 * ft + ln];
        for (int vi = 0; vi < myCnt; ++vi) {
            const int row = (myBase + vi) * 16 + ln;
            const short8 af1 = *(const short8*)&A1[row * A_S + 8 * q];
            const short8 af2 = *(const short8*)&A2[row * A_S + 8 * q];
            #pragma unroll
            for (int ft = 0; ft < 4; ++ft) {
                acc1[vi][ft] = __builtin_amdgcn_mfma_f32_16x16x32_bf16(af1, bfr[ft], acc1[vi][ft], 0, 0, 0);
                acc2[vi][ft] = __builtin_amdgcn_mfma_f32_16x16x32_bf16(af2, bfr[ft], acc2[vi][ft], 0, 0, 0);
            }
        }
    }

    // ---- epilogue ----
    const int vg = tid >> 4, fg = tid & 15;
    const int v0 = vg * 13, f0 = 4 * fg;
    float4 o[13];
    #pragma unroll
    for (int j = 0; j < 13; ++j) o[j] = make_float4(0.f, 0.f, 0.f, 0.f);

    // k=0: contract bf16 x (still in xs) with Theta0, then scale by Att diag
    for (int i4 = 0; i4 < 16; ++i4) {
        const int f4 = 4 * ((i4 + 4 * vg) & 15);
        const float4 t0 = *(const float4*)&Theta[(f4 + 0) * FO + f0];
        const float4 t1 = *(const float4*)&Theta[(f4 + 1) * FO + f0];
        const float4 t2 = *(const float4*)&Theta[(f4 + 2) * FO + f0];
        const float4 t3 = *(const float4*)&Theta[(f4 + 3) * FO + f0];
        #pragma unroll
        for (int j = 0; j < 13; ++j) {
            const int v = v0 + j;
            const u16x4 xw = *(const u16x4*)&xs[v * XS_S + f4];
            fma4(o[j], bf2f(xw[0]), t0); fma4(o[j], bf2f(xw[1]), t1);
            fma4(o[j], bf2f(xw[2]), t2); fma4(o[j], bf2f(xw[3]), t3);
        }
    }
    #pragma unroll
    for (int j = 0; j < 13; ++j) {
        const float av = adbuf[v0 + j];
        o[j].x *= av; o[j].y *= av; o[j].z *= av; o[j].w *= av;
    }

    // k=1,2: dump acc tiles (C-layout: col=lane&15, row=(lane>>4)*4+reg) to ys,
    // ADDING the fp32 diagonal term dc_k[v] * x[v,f] (x reloaded fp32, L2-hot),
    // then fp32 contract with Theta_k
    for (int k = 1; k <= 2; ++k) {
        __syncthreads();   // xs reads (k=1) / prev ys reads (k=2) done
        for (int vi = 0; vi < myCnt; ++vi) {
            const int vt = myBase + vi;
            float dc[4];
            #pragma unroll
            for (int reg = 0; reg < 4; ++reg) {
                const int v = vt * 16 + 4 * q + reg;
                float d = 0.f;
                if (v < V) {
                    const float cc = cbuf[v];
                    d = ((k == 1) ? cc : (2.0f * cc * cc - 1.0f)) * adbuf[v];
                }
                dc[reg] = d;
            }
            #pragma unroll
            for (int ft = 0; ft < 4; ++ft) {
                const f32x4 a = (k == 1) ? acc1[vi][ft] : acc2[vi][ft];
                #pragma unroll
                for (int reg = 0; reg < 4; ++reg) {
                    const int v = vt * 16 + 4 * q + reg;
                    const float xv = (v < V) ? xp[v * F + 16 * ft + ln] : 0.f;
                    ys[v * YS_S + 16 * ft + ln] = a[reg] + dc[reg] * xv;
                }
            }
        }
        __syncthreads();
        const float* __restrict__ Th = Theta + k * (F * FO);
        for (int i4 = 0; i4 < 16; ++i4) {
            const int f4 = 4 * ((i4 + 4 * vg) & 15);
            const float4 t0 = *(const float4*)&Th[(f4 + 0) * FO + f0];
            const float4 t1 = *(const float4*)&Th[(f4 + 1) * FO + f0];
            const float4 t2 = *(const float4*)&Th[(f4 + 2) * FO + f0];
            const float4 t3 = *(const float4*)&Th[(f4 + 3) * FO + f0];
            #pragma unroll
            for (int j = 0; j < 13; ++j) {
                const float4 yv = *(const float4*)&ys[(v0 + j) * YS_S + f4];
                fma4(o[j], yv.x, t0); fma4(o[j], yv.y, t1);
                fma4(o[j], yv.z, t2); fma4(o[j], yv.w, t3);
            }
        }
    }

    // relu + store
    #pragma unroll
    for (int j = 0; j < 13; ++j) {
        const int v = v0 + j;
        if (v < V) {
            float4 r = o[j];
            r.x = fmaxf(r.x, 0.f); r.y = fmaxf(r.y, 0.f);
            r.z = fmaxf(r.z, 0.f); r.w = fmaxf(r.w, 0.f);
            *(float4*)&op[v * FO + f0] = r;
        }
    }
}

} // namespace

extern "C" void kernel_launch(void* const* d_in, const int* in_sizes, int n_in,
                              void* d_out, int out_size, void* d_ws, size_t ws_size,
                              hipStream_t stream) {
    const float* x     = (const float*)d_in[0];
    const float* Att   = (const float*)d_in[1];
    const float* S     = (const float*)d_in[2];
    const float* Theta = (const float*)d_in[3];
    float* out         = (float*)d_out;

    char* ws = (char*)d_ws;
    unsigned short* smin = (unsigned short*)(ws + WS_SMIN);
    float* c_ws  = (float*)(ws + WS_C);
    float* attT  = (float*)(ws + WS_ATTT);
    float* adiag = (float*)(ws + WS_ADIAG);

    hipLaunchKernelGGL(prep_smin, dim3(NT, 7), dim3(256), 0, stream, S, smin, c_ws);
    hipLaunchKernelGGL(prep_att,  dim3(8, 49), dim3(256), 0, stream, Att, attT, adiag);
    hipLaunchKernelGGL(cheb_main, dim3(NT),    dim3(256), 0, stream,
                       x, Theta, smin, c_ws, attT, adiag, out);
}

// Round 4
// 307.157 us; speedup vs baseline: 1.4236x; 1.4236x over previous
//
#include <hip/hip_runtime.h>

namespace {

typedef __attribute__((ext_vector_type(8)))  short          short8;
typedef __attribute__((ext_vector_type(8)))  unsigned short u16x8;
typedef __attribute__((ext_vector_type(4)))  unsigned short u16x4;
typedef __attribute__((ext_vector_type(4)))  float          f32x4;

constexpr int V   = 200;
constexpr int VP  = 208;   // v padded (13 x 16)
constexpr int UP  = 224;   // u padded (7 x 32)
constexpr int F   = 64;
constexpr int FO  = 64;
constexpr int NT  = 512;   // N*T

// ---- ws layout (bytes) ----
constexpr size_t WS_SMIN  = 0;                         // ushort [512][208][224] = 47,710,208
constexpr size_t WS_C     = 47710208;                  // float  [512][208]     =    425,984
constexpr size_t WS_ATTT  = 48136192;                  // float  [8][224][224]  =  1,605,632
constexpr size_t WS_ADIAG = 49741824;                  // float  [8][224]       =      7,168

__device__ __forceinline__ unsigned short f2bf(float x) {
    union { float f; unsigned u; } c; c.f = x;
    unsigned r = c.u + 0x7FFF + ((c.u >> 16) & 1);
    return (unsigned short)(r >> 16);
}
__device__ __forceinline__ float bf2f(unsigned short h) {
    union { unsigned u; float f; } c; c.u = ((unsigned)h) << 16;
    return c.f;
}
__device__ __forceinline__ void fma4(float4& o, float s, const float4& t) {
    o.x += s * t.x; o.y += s * t.y; o.z += s * t.z; o.w += s * t.w;
}

// ============ P1: S_min (bf16, padded) + c[v] = d[v]-1-S[v][v] ============
__global__ __launch_bounds__(256)
void prep_smin(const float* __restrict__ S,
               unsigned short* __restrict__ smin,
               float* __restrict__ c_ws)
{
    __shared__ float rowbuf[32][204];   // S[band rows][0..200) , then m (in-place)
    __shared__ float colbuf[200][36];   // S[all rows][band cols]
    __shared__ float dpart[32][8];

    const int b    = blockIdx.x;
    const int band = blockIdx.y;
    const int tid  = threadIdx.x;
    const float* __restrict__ Sp = S + (size_t)b * (V * V);

    for (int idx = tid; idx < 32 * 50; idx += 256) {
        const int r = idx / 50, ch = idx % 50;
        const int rg = band * 32 + r;
        float4 v = make_float4(0.f, 0.f, 0.f, 0.f);
        if (rg < V) v = *(const float4*)&Sp[rg * V + 4 * ch];
        rowbuf[r][4 * ch + 0] = v.x; rowbuf[r][4 * ch + 1] = v.y;
        rowbuf[r][4 * ch + 2] = v.z; rowbuf[r][4 * ch + 3] = v.w;
    }
    for (int idx = tid; idx < 200 * 8; idx += 256) {
        const int j = idx >> 3, ch = idx & 7;
        float4 v = make_float4(0.f, 0.f, 0.f, 0.f);
        if (8 * band + ch <= 49)
            v = *(const float4*)&Sp[j * V + band * 32 + 4 * ch];
        colbuf[j][4 * ch + 0] = v.x; colbuf[j][4 * ch + 1] = v.y;
        colbuf[j][4 * ch + 2] = v.z; colbuf[j][4 * ch + 3] = v.w;
    }
    __syncthreads();

    const int r = tid >> 3, cseg = tid & 7;
    float dp = 0.f;
    for (int jj = 0; jj < 28; ++jj) {
        const int j = 28 * cseg + jj;
        if (j < V) {
            const float m = fminf(rowbuf[r][j], colbuf[j][r]);
            rowbuf[r][j] = m;
            dp += m;
        }
    }
    dpart[r][cseg] = dp;
    __syncthreads();

    if (tid < 32) {
        const int vg = band * 32 + tid;
        if (vg < VP) {
            float cv = 0.f;
            if (vg < V) {
                float d = 0.f;
                #pragma unroll
                for (int cc = 0; cc < 8; ++cc) d += dpart[tid][cc];
                cv = d - 1.0f - rowbuf[tid][vg];
            }
            c_ws[b * VP + vg] = cv;
        }
    }

    for (int idx = tid; idx < 32 * 28; idx += 256) {
        const int rr = idx / 28, ch = idx % 28;
        const int vg = band * 32 + rr;
        if (vg < VP) {
            u16x8 o;
            #pragma unroll
            for (int jj = 0; jj < 8; ++jj) {
                const int j = 8 * ch + jj;
                o[jj] = (j < V) ? f2bf(rowbuf[rr][j]) : (unsigned short)0;
            }
            *(u16x8*)&smin[(size_t)b * (VP * UP) + vg * UP + 8 * ch] = o;
        }
    }
}

// ============ P2: AttT[n][v][u] = Att[n][u][v] (fp32, zero-padded) + diag ====
__global__ __launch_bounds__(256)
void prep_att(const float* __restrict__ Att,
              float* __restrict__ attT,
              float* __restrict__ adiag)
{
    __shared__ float T[32][33];
    const int n  = blockIdx.x;
    const int ut = blockIdx.y / 7, vt = blockIdx.y % 7;
    const int tid = threadIdx.x;

    for (int idx = tid; idx < 1024; idx += 256) {
        const int rr = idx >> 5, cc = idx & 31;
        const int u = 32 * ut + rr, v = 32 * vt + cc;
        T[rr][cc] = (u < V && v < V) ? Att[(size_t)n * (V * V) + u * V + v] : 0.f;
    }
    __syncthreads();
    for (int idx = tid; idx < 1024; idx += 256) {
        const int r2 = idx >> 5, c2 = idx & 31;
        attT[(size_t)n * (UP * UP) + (32 * vt + r2) * UP + 32 * ut + c2] = T[c2][r2];
    }
    if (ut == vt && tid < 32)
        adiag[n * UP + 32 * vt + tid] = T[tid][tid];
}

// ============ G: MFMA main loop (off-diag bf16) + fp32 diag + fp32 epilogue ==
constexpr int XS_S = 68;   // xs stride (bf16 elems)
constexpr int A_S  = 40;   // A-tile stride (bf16 elems)
constexpr int YS_S = 68;   // ys stride (f32)

__global__ __launch_bounds__(256, 2)
void cheb_main(const float* __restrict__ x,
               const float* __restrict__ Theta,
               const unsigned short* __restrict__ smin,
               const float* __restrict__ c_ws,
               const float* __restrict__ attT,
               const float* __restrict__ adiag,
               float* __restrict__ out)
{
    __shared__ __align__(16) char smem[65408];
    unsigned short* xs = (unsigned short*)smem;                    // 30,464 B
    unsigned short* A1 = (unsigned short*)(smem + 30464);          // 16,640 B
    unsigned short* A2 = (unsigned short*)(smem + 47104);          // 16,640 B
    float*          ys = (float*)smem;                             // 56,576 B (epilogue)
    float*        cbuf = (float*)(smem + 63744);                   //    832 B
    float*       adbuf = (float*)(smem + 64576);                   //    832 B

    const int tid = threadIdx.x;
    const int b   = blockIdx.x;
    const int n   = b >> 6;
    const float* __restrict__ xp = x + (size_t)b * (V * F);
    const unsigned short* __restrict__ sm = smin + (size_t)b * (VP * UP);
    const float* __restrict__ atp = attT + (size_t)n * (UP * UP);
    float* __restrict__ op = out + (size_t)b * (V * FO);

    // ---- stage x -> bf16 xs[u][f] (zeros for u >= 200) ----
    for (int idx = tid; idx < UP * 16; idx += 256) {
        const int u = idx >> 4, fg = idx & 15;
        u16x4 w; w[0] = 0; w[1] = 0; w[2] = 0; w[3] = 0;
        if (u < V) {
            const float4 v = *(const float4*)&xp[u * F + 4 * fg];
            w[0] = f2bf(v.x); w[1] = f2bf(v.y); w[2] = f2bf(v.z); w[3] = f2bf(v.w);
        }
        *(u16x4*)&xs[u * XS_S + 4 * fg] = w;
    }
    if (tid < VP) {
        cbuf[tid]  = c_ws[b * VP + tid];
        adbuf[tid] = adiag[n * UP + tid];
    }

    const int wave = tid >> 6, lane = tid & 63;
    const int q = lane >> 4, ln = lane & 15;
    // 13 v-tiles split 4/3/3/3 across waves; myBase/myCnt are wave-uniform and
    // ALL acc indexing below is compile-time static (vi fully unrolled) so the
    // accumulators stay in registers (R3: runtime vi bound spilled them).
    const int myBase = (wave == 0) ? 0 : (4 + 3 * (wave - 1));
    const int myCnt  = (wave == 0) ? 4 : 3;

    f32x4 acc1[4][4], acc2[4][4];
    #pragma unroll
    for (int i = 0; i < 4; ++i)
        #pragma unroll
        for (int j = 0; j < 4; ++j) {
            acc1[i][j] = (f32x4)0.f; acc2[i][j] = (f32x4)0.f;
        }

    // ---- K loop: 7 steps of 32 u's; diagonal (u==v) EXCLUDED from bf16 path ----
    for (int kt = 0; kt < 7; ++kt) {
        const int u0 = 32 * kt;
        __syncthreads();
        for (int idx = tid; idx < VP * 4; idx += 256) {
            const int v = idx >> 2, ch = idx & 3;
            const int u8 = u0 + 8 * ch;
            const u16x8 s8 = *(const u16x8*)&sm[v * UP + u8];
            const float4 a0 = *(const float4*)&atp[v * UP + u8];
            const float4 a1 = *(const float4*)&atp[v * UP + u8 + 4];
            float att[8] = {a0.x, a0.y, a0.z, a0.w, a1.x, a1.y, a1.z, a1.w};
            u16x8 w1, w2;
            #pragma unroll
            for (int jj = 0; jj < 8; ++jj) {
                const float m = bf2f(s8[jj]);
                if (u8 + jj == v) {        // diagonal handled in fp32 epilogue
                    w1[jj] = 0; w2[jj] = 0;
                } else {
                    w1[jj] = f2bf(-m * att[jj]);
                    w2[jj] = f2bf(2.0f * m * m * att[jj]);
                }
            }
            *(u16x8*)&A1[v * A_S + 8 * ch] = w1;
            *(u16x8*)&A2[v * A_S + 8 * ch] = w2;
        }
        __syncthreads();
        short8 bfr[4];
        #pragma unroll
        for (int ft = 0; ft < 4; ++ft)
            #pragma unroll
            for (int j = 0; j < 8; ++j)
                bfr[ft][j] = (short)xs[(u0 + 8 * q + j) * XS_S + 16 * ft + ln];
        #pragma unroll
        for (int vi = 0; vi < 4; ++vi) {
            if (vi < myCnt) {                       // wave-uniform guard
                const int row = (myBase + vi) * 16 + ln;
                const short8 af1 = *(const short8*)&A1[row * A_S + 8 * q];
                const short8 af2 = *(const short8*)&A2[row * A_S + 8 * q];
                #pragma unroll
                for (int ft = 0; ft < 4; ++ft) {
                    acc1[vi][ft] = __builtin_amdgcn_mfma_f32_16x16x32_bf16(af1, bfr[ft], acc1[vi][ft], 0, 0, 0);
                    acc2[vi][ft] = __builtin_amdgcn_mfma_f32_16x16x32_bf16(af2, bfr[ft], acc2[vi][ft], 0, 0, 0);
                }
            }
        }
    }

    // ---- epilogue ----
    const int vg = tid >> 4, fg = tid & 15;
    const int v0 = vg * 13, f0 = 4 * fg;
    float4 o[13];
    #pragma unroll
    for (int j = 0; j < 13; ++j) o[j] = make_float4(0.f, 0.f, 0.f, 0.f);

    // k=0: contract bf16 x (still in xs) with Theta0, then scale by Att diag
    for (int i4 = 0; i4 < 16; ++i4) {
        const int f4 = 4 * ((i4 + 4 * vg) & 15);
        const float4 t0 = *(const float4*)&Theta[(f4 + 0) * FO + f0];
        const float4 t1 = *(const float4*)&Theta[(f4 + 1) * FO + f0];
        const float4 t2 = *(const float4*)&Theta[(f4 + 2) * FO + f0];
        const float4 t3 = *(const float4*)&Theta[(f4 + 3) * FO + f0];
        #pragma unroll
        for (int j = 0; j < 13; ++j) {
            const int v = v0 + j;
            const u16x4 xw = *(const u16x4*)&xs[v * XS_S + f4];
            fma4(o[j], bf2f(xw[0]), t0); fma4(o[j], bf2f(xw[1]), t1);
            fma4(o[j], bf2f(xw[2]), t2); fma4(o[j], bf2f(xw[3]), t3);
        }
    }
    #pragma unroll
    for (int j = 0; j < 13; ++j) {
        const float av = adbuf[v0 + j];
        o[j].x *= av; o[j].y *= av; o[j].z *= av; o[j].w *= av;
    }

    // k=1,2: dump acc tiles + fp32 diag term, then fp32 contract with Theta_k
    #pragma unroll
    for (int k = 1; k <= 2; ++k) {
        __syncthreads();
        #pragma unroll
        for (int vi = 0; vi < 4; ++vi) {
            if (vi < myCnt) {
                const int vt = myBase + vi;
                float dc[4];
                #pragma unroll
                for (int reg = 0; reg < 4; ++reg) {
                    const int v = vt * 16 + 4 * q + reg;
                    float d = 0.f;
                    if (v < V) {
                        const float cc = cbuf[v];
                        d = ((k == 1) ? cc : (2.0f * cc * cc - 1.0f)) * adbuf[v];
                    }
                    dc[reg] = d;
                }
                #pragma unroll
                for (int ft = 0; ft < 4; ++ft) {
                    const f32x4 a = (k == 1) ? acc1[vi][ft] : acc2[vi][ft];
                    #pragma unroll
                    for (int reg = 0; reg < 4; ++reg) {
                        const int v = vt * 16 + 4 * q + reg;
                        const float xv = (v < V) ? xp[v * F + 16 * ft + ln] : 0.f;
                        ys[v * YS_S + 16 * ft + ln] = a[reg] + dc[reg] * xv;
                    }
                }
            }
        }
        __syncthreads();
        const float* __restrict__ Th = Theta + k * (F * FO);
        for (int i4 = 0; i4 < 16; ++i4) {
            const int f4 = 4 * ((i4 + 4 * vg) & 15);
            const float4 t0 = *(const float4*)&Th[(f4 + 0) * FO + f0];
            const float4 t1 = *(const float4*)&Th[(f4 + 1) * FO + f0];
            const float4 t2 = *(const float4*)&Th[(f4 + 2) * FO + f0];
            const float4 t3 = *(const float4*)&Th[(f4 + 3) * FO + f0];
            #pragma unroll
            for (int j = 0; j < 13; ++j) {
                const float4 yv = *(const float4*)&ys[(v0 + j) * YS_S + f4];
                fma4(o[j], yv.x, t0); fma4(o[j], yv.y, t1);
                fma4(o[j], yv.z, t2); fma4(o[j], yv.w, t3);
            }
        }
    }

    // relu + store
    #pragma unroll
    for (int j = 0; j < 13; ++j) {
        const int v = v0 + j;
        if (v < V) {
            float4 r = o[j];
            r.x = fmaxf(r.x, 0.f); r.y = fmaxf(r.y, 0.f);
            r.z = fmaxf(r.z, 0.f); r.w = fmaxf(r.w, 0.f);
            *(float4*)&op[v * FO + f0] = r;
        }
    }
}

} // namespace

extern "C" void kernel_launch(void* const* d_in, const int* in_sizes, int n_in,
                              void* d_out, int out_size, void* d_ws, size_t ws_size,
                              hipStream_t stream) {
    const float* x     = (const float*)d_in[0];
    const float* Att   = (const float*)d_in[1];
    const float* S     = (const float*)d_in[2];
    const float* Theta = (const float*)d_in[3];
    float* out         = (float*)d_out;

    char* ws = (char*)d_ws;
    unsigned short* smin = (unsigned short*)(ws + WS_SMIN);
    float* c_ws  = (float*)(ws + WS_C);
    float* attT  = (float*)(ws + WS_ATTT);
    float* adiag = (float*)(ws + WS_ADIAG);

    hipLaunchKernelGGL(prep_smin, dim3(NT, 7), dim3(256), 0, stream, S, smin, c_ws);
    hipLaunchKernelGGL(prep_att,  dim3(8, 49), dim3(256), 0, stream, Att, attT, adiag);
    hipLaunchKernelGGL(cheb_main, dim3(NT),    dim3(256), 0, stream,
                       x, Theta, smin, c_ws, attT, adiag, out);
}

// Round 5
// 285.788 us; speedup vs baseline: 1.5300x; 1.0748x over previous
//
#include <hip/hip_runtime.h>

namespace {

typedef __attribute__((ext_vector_type(8)))  short          short8;
typedef __attribute__((ext_vector_type(8)))  unsigned short u16x8;
typedef __attribute__((ext_vector_type(4)))  unsigned short u16x4;
typedef __attribute__((ext_vector_type(4)))  float          f32x4;

constexpr int V   = 200;
constexpr int VP  = 208;   // v padded (13 x 16)
constexpr int UP  = 224;   // u padded (7 x 32)
constexpr int F   = 64;
constexpr int FO  = 64;
constexpr int NT  = 512;   // N*T

// ---- ws layout (bytes) ----
constexpr size_t WS_SMIN  = 0;                         // ushort [512][208][224] = 47,710,208
constexpr size_t WS_C     = 47710208;                  // float  [512][208]     =    425,984
constexpr size_t WS_ATTT  = 48136192;                  // float  [8][224][224]  =  1,605,632
constexpr size_t WS_ADIAG = 49741824;                  // float  [8][224]       =      7,168
constexpr size_t WS_THT   = 49748992;                  // ushort [3][64][64]    =     24,576

__device__ __forceinline__ unsigned short f2bf(float x) {
    union { float f; unsigned u; } c; c.f = x;
    unsigned r = c.u + 0x7FFF + ((c.u >> 16) & 1);
    return (unsigned short)(r >> 16);
}
__device__ __forceinline__ float bf2f(unsigned short h) {
    union { unsigned u; float f; } c; c.u = ((unsigned)h) << 16;
    return c.f;
}

// ============ P1: S_min (bf16, padded) + c[v] = d[v]-1-S[v][v] ============
__global__ __launch_bounds__(256)
void prep_smin(const float* __restrict__ S,
               unsigned short* __restrict__ smin,
               float* __restrict__ c_ws)
{
    __shared__ float rowbuf[32][204];
    __shared__ float colbuf[200][36];
    __shared__ float dpart[32][8];

    const int b    = blockIdx.x;
    const int band = blockIdx.y;
    const int tid  = threadIdx.x;
    const float* __restrict__ Sp = S + (size_t)b * (V * V);

    for (int idx = tid; idx < 32 * 50; idx += 256) {
        const int r = idx / 50, ch = idx % 50;
        const int rg = band * 32 + r;
        float4 v = make_float4(0.f, 0.f, 0.f, 0.f);
        if (rg < V) v = *(const float4*)&Sp[rg * V + 4 * ch];
        rowbuf[r][4 * ch + 0] = v.x; rowbuf[r][4 * ch + 1] = v.y;
        rowbuf[r][4 * ch + 2] = v.z; rowbuf[r][4 * ch + 3] = v.w;
    }
    for (int idx = tid; idx < 200 * 8; idx += 256) {
        const int j = idx >> 3, ch = idx & 7;
        float4 v = make_float4(0.f, 0.f, 0.f, 0.f);
        if (8 * band + ch <= 49)
            v = *(const float4*)&Sp[j * V + band * 32 + 4 * ch];
        colbuf[j][4 * ch + 0] = v.x; colbuf[j][4 * ch + 1] = v.y;
        colbuf[j][4 * ch + 2] = v.z; colbuf[j][4 * ch + 3] = v.w;
    }
    __syncthreads();

    const int r = tid >> 3, cseg = tid & 7;
    float dp = 0.f;
    for (int jj = 0; jj < 28; ++jj) {
        const int j = 28 * cseg + jj;
        if (j < V) {
            const float m = fminf(rowbuf[r][j], colbuf[j][r]);
            rowbuf[r][j] = m;
            dp += m;
        }
    }
    dpart[r][cseg] = dp;
    __syncthreads();

    if (tid < 32) {
        const int vg = band * 32 + tid;
        if (vg < VP) {
            float cv = 0.f;
            if (vg < V) {
                float d = 0.f;
                #pragma unroll
                for (int cc = 0; cc < 8; ++cc) d += dpart[tid][cc];
                cv = d - 1.0f - rowbuf[tid][vg];
            }
            c_ws[b * VP + vg] = cv;
        }
    }

    for (int idx = tid; idx < 32 * 28; idx += 256) {
        const int rr = idx / 28, ch = idx % 28;
        const int vg = band * 32 + rr;
        if (vg < VP) {
            u16x8 o;
            #pragma unroll
            for (int jj = 0; jj < 8; ++jj) {
                const int j = 8 * ch + jj;
                o[jj] = (j < V) ? f2bf(rowbuf[rr][j]) : (unsigned short)0;
            }
            *(u16x8*)&smin[(size_t)b * (VP * UP) + vg * UP + 8 * ch] = o;
        }
    }
}

// ============ P2: AttT[n][v][u] = Att[n][u][v] (fp32, zero-padded) + diag ====
__global__ __launch_bounds__(256)
void prep_att(const float* __restrict__ Att,
              float* __restrict__ attT,
              float* __restrict__ adiag)
{
    __shared__ float T[32][33];
    const int n  = blockIdx.x;
    const int ut = blockIdx.y / 7, vt = blockIdx.y % 7;
    const int tid = threadIdx.x;

    for (int idx = tid; idx < 1024; idx += 256) {
        const int rr = idx >> 5, cc = idx & 31;
        const int u = 32 * ut + rr, v = 32 * vt + cc;
        T[rr][cc] = (u < V && v < V) ? Att[(size_t)n * (V * V) + u * V + v] : 0.f;
    }
    __syncthreads();
    for (int idx = tid; idx < 1024; idx += 256) {
        const int r2 = idx >> 5, c2 = idx & 31;
        attT[(size_t)n * (UP * UP) + (32 * vt + r2) * UP + 32 * ut + c2] = T[c2][r2];
    }
    if (ut == vt && tid < 32)
        adiag[n * UP + 32 * vt + tid] = T[tid][tid];
}

// ============ P3: ThT[k][fo][f] = bf16(Theta[k][f][fo]) ============
__global__ __launch_bounds__(256)
void prep_theta(const float* __restrict__ Theta,
                unsigned short* __restrict__ thT)
{
    __shared__ float T[64][65];
    const int k = blockIdx.x, tid = threadIdx.x;
    for (int idx = tid; idx < 4096; idx += 256)
        T[idx >> 6][idx & 63] = Theta[k * 4096 + idx];
    __syncthreads();
    for (int idx = tid; idx < 4096; idx += 256) {
        const int fo = idx >> 6, f = idx & 63;
        thT[k * 4096 + fo * 64 + f] = f2bf(T[f][fo]);
    }
}

// ============ G: MFMA main loop + MFMA Theta epilogue ============
constexpr int XS_S = 68;   // xs stride (bf16)
constexpr int A_S  = 40;   // A-tile stride (bf16)
constexpr int YS_S = 72;   // ys / ThS stride (bf16)

__global__ __launch_bounds__(256, 2)
void cheb_main(const float* __restrict__ x,
               const unsigned short* __restrict__ thT,
               const unsigned short* __restrict__ smin,
               const float* __restrict__ c_ws,
               const float* __restrict__ attT,
               const float* __restrict__ adiag,
               float* __restrict__ out)
{
    __shared__ __align__(16) char smem[65408];
    unsigned short* xs  = (unsigned short*)smem;            // [224][68] = 30,464 B
    unsigned short* A1  = (unsigned short*)(smem + 30464);  // [208][40] = 16,640 B
    unsigned short* A2  = (unsigned short*)(smem + 47104);  // [208][40] = 16,640 B
    unsigned short* ys  = (unsigned short*)smem;            // [208][72] = 29,952 B (epilogue)
    unsigned short* ThS = (unsigned short*)(smem + 30464);  // [64][72]  =  9,216 B (epilogue)
    float*        cbuf  = (float*)(smem + 63744);           // 832 B
    float*       adbuf  = (float*)(smem + 64576);           // 832 B

    const int tid = threadIdx.x;
    const int b   = blockIdx.x;
    const int n   = b >> 6;
    const float* __restrict__ xp = x + (size_t)b * (V * F);
    const unsigned short* __restrict__ sm = smin + (size_t)b * (VP * UP);
    const float* __restrict__ atp = attT + (size_t)n * (UP * UP);
    float* __restrict__ op = out + (size_t)b * (V * FO);

    // ---- stage x -> bf16 xs[u][f] (zeros for u >= 200) ----
    for (int idx = tid; idx < UP * 16; idx += 256) {
        const int u = idx >> 4, fg = idx & 15;
        u16x4 w; w[0] = 0; w[1] = 0; w[2] = 0; w[3] = 0;
        if (u < V) {
            const float4 v = *(const float4*)&xp[u * F + 4 * fg];
            w[0] = f2bf(v.x); w[1] = f2bf(v.y); w[2] = f2bf(v.z); w[3] = f2bf(v.w);
        }
        *(u16x4*)&xs[u * XS_S + 4 * fg] = w;
    }
    if (tid < VP) {
        cbuf[tid]  = c_ws[b * VP + tid];
        adbuf[tid] = adiag[n * UP + tid];
    }

    const int wave = tid >> 6, lane = tid & 63;
    const int q = lane >> 4, ln = lane & 15;
    const int myBase = (wave == 0) ? 0 : (4 + 3 * (wave - 1));
    const int myCnt  = (wave == 0) ? 4 : 3;

    f32x4 acc1[4][4], acc2[4][4];
    #pragma unroll
    for (int i = 0; i < 4; ++i)
        #pragma unroll
        for (int j = 0; j < 4; ++j) {
            acc1[i][j] = (f32x4)0.f; acc2[i][j] = (f32x4)0.f;
        }

    // ---- software-pipelined A-build input prefetch (regs) ----
    u16x8 pf_s[4]; float4 pf_a0[4], pf_a1[4];
    auto load_chunks = [&](int kt) {
        const int u0 = 32 * kt;
        #pragma unroll
        for (int c = 0; c < 4; ++c) {
            const int idx = tid + 256 * c;
            if (idx < VP * 4) {
                const int v = idx >> 2, ch = idx & 3;
                const int u8 = u0 + 8 * ch;
                pf_s[c]  = *(const u16x8*)&sm[v * UP + u8];
                pf_a0[c] = *(const float4*)&atp[v * UP + u8];
                pf_a1[c] = *(const float4*)&atp[v * UP + u8 + 4];
            }
        }
    };
    load_chunks(0);

    // ---- K loop: 7 steps of 32 u's; diagonal (u==v) excluded (fp32 later) ----
    for (int kt = 0; kt < 7; ++kt) {
        const int u0 = 32 * kt;
        __syncthreads();                 // A region free / xs ready (kt=0)
        #pragma unroll
        for (int c = 0; c < 4; ++c) {
            const int idx = tid + 256 * c;
            if (idx < VP * 4) {
                const int v = idx >> 2, ch = idx & 3;
                const int u8 = u0 + 8 * ch;
                const u16x8 s8 = pf_s[c];
                const float att[8] = {pf_a0[c].x, pf_a0[c].y, pf_a0[c].z, pf_a0[c].w,
                                      pf_a1[c].x, pf_a1[c].y, pf_a1[c].z, pf_a1[c].w};
                u16x8 w1, w2;
                #pragma unroll
                for (int jj = 0; jj < 8; ++jj) {
                    const float m = bf2f(s8[jj]);
                    if (u8 + jj == v) { w1[jj] = 0; w2[jj] = 0; }
                    else {
                        w1[jj] = f2bf(-m * att[jj]);
                        w2[jj] = f2bf(2.0f * m * m * att[jj]);
                    }
                }
                *(u16x8*)&A1[v * A_S + 8 * ch] = w1;
                *(u16x8*)&A2[v * A_S + 8 * ch] = w2;
            }
        }
        if (kt < 6) load_chunks(kt + 1);     // latency overlaps barrier+MFMA
        __syncthreads();
        short8 bfr[4];
        #pragma unroll
        for (int ft = 0; ft < 4; ++ft)
            #pragma unroll
            for (int j = 0; j < 8; ++j)
                bfr[ft][j] = (short)xs[(u0 + 8 * q + j) * XS_S + 16 * ft + ln];
        #pragma unroll
        for (int vi = 0; vi < 4; ++vi) {
            if (vi < myCnt) {
                const int row = (myBase + vi) * 16 + ln;
                const short8 af1 = *(const short8*)&A1[row * A_S + 8 * q];
                const short8 af2 = *(const short8*)&A2[row * A_S + 8 * q];
                #pragma unroll
                for (int ft = 0; ft < 4; ++ft) {
                    acc1[vi][ft] = __builtin_amdgcn_mfma_f32_16x16x32_bf16(af1, bfr[ft], acc1[vi][ft], 0, 0, 0);
                    acc2[vi][ft] = __builtin_amdgcn_mfma_f32_16x16x32_bf16(af2, bfr[ft], acc2[vi][ft], 0, 0, 0);
                }
            }
        }
    }

    // ---- epilogue: out-tiles += mfma(ys_k, ThT_k) for k = 1, 2, 0 ----
    f32x4 ot[4][4];
    #pragma unroll
    for (int i = 0; i < 4; ++i)
        #pragma unroll
        for (int j = 0; j < 4; ++j) ot[i][j] = (f32x4)0.f;

    #pragma unroll
    for (int pass = 0; pass < 3; ++pass) {
        const int k = (pass == 0) ? 1 : (pass == 1) ? 2 : 0;
        __syncthreads();   // prev contract / main loop reads done

        if (k == 0) {
            // ys0[v][f] = Att_vv * x[v][f]  (bf16), zero pad rows
            for (int idx = tid; idx < VP * 16; idx += 256) {
                const int v = idx >> 4, fg = idx & 15;
                u16x4 w; w[0] = 0; w[1] = 0; w[2] = 0; w[3] = 0;
                if (v < V) {
                    const float av = adbuf[v];
                    const float4 xv = *(const float4*)&xp[v * F + 4 * fg];
                    w[0] = f2bf(av * xv.x); w[1] = f2bf(av * xv.y);
                    w[2] = f2bf(av * xv.z); w[3] = f2bf(av * xv.w);
                }
                *(u16x4*)&ys[v * YS_S + 4 * fg] = w;
            }
        } else {
            // ys_k[v][f] = acc_k + dc_k[v] * x[v][f]  (bf16; diag in fp32 here)
            #pragma unroll
            for (int vi = 0; vi < 4; ++vi) {
                if (vi < myCnt) {
                    const int vt = myBase + vi;
                    #pragma unroll
                    for (int ft = 0; ft < 4; ++ft) {
                        const f32x4 a = (k == 1) ? acc1[vi][ft] : acc2[vi][ft];
                        #pragma unroll
                        for (int reg = 0; reg < 4; ++reg) {
                            const int v = vt * 16 + 4 * q + reg;
                            float val = 0.f;
                            if (v < V) {
                                const float cc = cbuf[v];
                                const float dc = ((k == 1) ? cc : (2.0f * cc * cc - 1.0f)) * adbuf[v];
                                val = a[reg] + dc * xp[v * F + 16 * ft + ln];
                            }
                            ys[v * YS_S + 16 * ft + ln] = f2bf(val);
                        }
                    }
                }
            }
        }
        // stage ThT_k -> ThS[fo][f]
        for (int idx = tid; idx < 64 * 8; idx += 256) {
            const int fo = idx >> 3, ch = idx & 7;
            *(u16x8*)&ThS[fo * YS_S + 8 * ch] =
                *(const u16x8*)&thT[k * 4096 + fo * 64 + 8 * ch];
        }
        __syncthreads();
        // contract: ot[vt][fot] += ys[16vt..][f] @ ThT[f][16fot..]
        #pragma unroll
        for (int vi = 0; vi < 4; ++vi) {
            if (vi < myCnt) {
                const int vrow = (myBase + vi) * 16 + ln;
                #pragma unroll
                for (int ks = 0; ks < 2; ++ks) {
                    const short8 af = *(const short8*)&ys[vrow * YS_S + 32 * ks + 8 * q];
                    #pragma unroll
                    for (int fot = 0; fot < 4; ++fot) {
                        const short8 bf = *(const short8*)&ThS[(16 * fot + ln) * YS_S + 32 * ks + 8 * q];
                        ot[vi][fot] = __builtin_amdgcn_mfma_f32_16x16x32_bf16(af, bf, ot[vi][fot], 0, 0, 0);
                    }
                }
            }
        }
    }

    // ---- relu + store (C-layout: row v = 4q+reg, col fo = ln) ----
    #pragma unroll
    for (int vi = 0; vi < 4; ++vi) {
        if (vi < myCnt) {
            const int vt = myBase + vi;
            #pragma unroll
            for (int fot = 0; fot < 4; ++fot) {
                #pragma unroll
                for (int reg = 0; reg < 4; ++reg) {
                    const int v = vt * 16 + 4 * q + reg;
                    if (v < V)
                        op[v * FO + 16 * fot + ln] = fmaxf(ot[vi][fot][reg], 0.f);
                }
            }
        }
    }
}

} // namespace

extern "C" void kernel_launch(void* const* d_in, const int* in_sizes, int n_in,
                              void* d_out, int out_size, void* d_ws, size_t ws_size,
                              hipStream_t stream) {
    const float* x     = (const float*)d_in[0];
    const float* Att   = (const float*)d_in[1];
    const float* S     = (const float*)d_in[2];
    const float* Theta = (const float*)d_in[3];
    float* out         = (float*)d_out;

    char* ws = (char*)d_ws;
    unsigned short* smin = (unsigned short*)(ws + WS_SMIN);
    float* c_ws  = (float*)(ws + WS_C);
    float* attT  = (float*)(ws + WS_ATTT);
    float* adiag = (float*)(ws + WS_ADIAG);
    unsigned short* thT = (unsigned short*)(ws + WS_THT);

    hipLaunchKernelGGL(prep_smin,  dim3(NT, 7), dim3(256), 0, stream, S, smin, c_ws);
    hipLaunchKernelGGL(prep_att,   dim3(8, 49), dim3(256), 0, stream, Att, attT, adiag);
    hipLaunchKernelGGL(prep_theta, dim3(3),     dim3(256), 0, stream, Theta, thT);
    hipLaunchKernelGGL(cheb_main,  dim3(NT),    dim3(256), 0, stream,
                       x, thT, smin, c_ws, attT, adiag, out);
}

// Round 6
// 239.081 us; speedup vs baseline: 1.8289x; 1.1954x over previous
//
#include <hip/hip_runtime.h>

namespace {

typedef __attribute__((ext_vector_type(8)))  short          short8;
typedef __attribute__((ext_vector_type(8)))  unsigned short u16x8;
typedef __attribute__((ext_vector_type(4)))  unsigned short u16x4;
typedef __attribute__((ext_vector_type(4)))  float          f32x4;

constexpr int V   = 200;
constexpr int VP  = 208;   // v padded (13 x 16)
constexpr int UP  = 224;   // u padded (7 x 32)
constexpr int F   = 64;
constexpr int FO  = 64;
constexpr int NT  = 512;   // N*T

// ---- ws layout (bytes) ----
constexpr size_t WS_SMIN  = 0;                         // ushort [512][208][224] = 47,710,208
constexpr size_t WS_D     = 47710208;                  // float  [512][208]     =    425,984 (atomic, memset 0)
constexpr size_t WS_SDIAG = 48136192;                  // float  [512][208]     =    425,984
constexpr size_t WS_ATTT  = 48562176;                  // float  [8][224][224]  =  1,605,632
constexpr size_t WS_ADIAG = 50167808;                  // float  [8][224]       =      7,168
constexpr size_t WS_THT   = 50174976;                  // ushort [3][64][64]    =     24,576

__device__ __forceinline__ unsigned short f2bf(float x) {
    union { float f; unsigned u; } c; c.f = x;
    unsigned r = c.u + 0x7FFF + ((c.u >> 16) & 1);
    return (unsigned short)(r >> 16);
}
__device__ __forceinline__ float bf2f(unsigned short h) {
    union { unsigned u; float f; } c; c.u = ((unsigned)h) << 16;
    return c.f;
}

// ============ P1: symmetric tile-pair S_min + d (atomic) + sdiag ============
// grid (512, 28): pair p -> (ti <= tj) over the 7x7 tile grid. Each S element
// is read exactly once; smin written at both orientations; d row-sums via
// wave shuffle-reduce + fp32 atomicAdd.
__global__ __launch_bounds__(256)
void prep_smin(const float* __restrict__ S,
               unsigned short* __restrict__ smin,
               float* __restrict__ d_ws,
               float* __restrict__ sdiag)
{
    __shared__ float As[32][33];
    __shared__ float Bs[32][33];
    __shared__ float Ms[32][33];

    const int b   = blockIdx.x;
    const int tid = threadIdx.x;
    int rem = blockIdx.y, ti = 0;
    while (rem >= 7 - ti) { rem -= 7 - ti; ++ti; }
    const int tj = ti + rem;
    const bool diag = (ti == tj);

    const float* __restrict__ Sp = S + (size_t)b * (V * V);
    unsigned short* __restrict__ smp = smin + (size_t)b * (VP * UP);

    const int r  = tid >> 3;      // 0..31
    const int cg = tid & 7;       // 0..7
    const int c0 = 4 * cg;

    // load A = S[32ti+r][32tj+c0..+3]; B = S[32tj+r][32ti+c0..+3]
    {
        const int gr = 32 * ti + r, gc = 32 * tj + c0;
        float4 a = make_float4(0.f, 0.f, 0.f, 0.f);
        if (gr < V && gc < V) a = *(const float4*)&Sp[gr * V + gc];  // V%4==0: no partial
        As[r][c0 + 0] = a.x; As[r][c0 + 1] = a.y; As[r][c0 + 2] = a.z; As[r][c0 + 3] = a.w;
        if (!diag) {
            const int hr = 32 * tj + r, hc = 32 * ti + c0;
            float4 bb = make_float4(0.f, 0.f, 0.f, 0.f);
            if (hr < V && hc < V) bb = *(const float4*)&Sp[hr * V + hc];
            Bs[r][c0 + 0] = bb.x; Bs[r][c0 + 1] = bb.y; Bs[r][c0 + 2] = bb.z; Bs[r][c0 + 3] = bb.w;
        }
    }
    __syncthreads();

    // M[r][c] = min(A[r][c], B[c][r]); row-sum -> d[32ti+r]
    float m[4], rs = 0.f;
    #pragma unroll
    for (int e = 0; e < 4; ++e) {
        const int c = c0 + e;
        const float tw = diag ? As[c][r] : Bs[c][r];
        m[e] = fminf(As[r][c], tw);
        Ms[r][c] = m[e];
        rs += m[e];
    }
    rs += __shfl_xor(rs, 1); rs += __shfl_xor(rs, 2); rs += __shfl_xor(rs, 4);
    if (cg == 0 && 32 * ti + r < V)
        atomicAdd(&d_ws[b * VP + 32 * ti + r], rs);
    if (diag && cg == 0 && 32 * ti + r < V)
        sdiag[b * VP + 32 * ti + r] = As[r][r];
    __syncthreads();   // Ms complete (needed for transposed reads/writes)

    // transposed col-sums -> d[32tj+r] (skip on diag: region counted once)
    if (!diag) {
        float ts = 0.f;
        #pragma unroll
        for (int e = 0; e < 4; ++e) ts += Ms[c0 + e][r];
        ts += __shfl_xor(ts, 1); ts += __shfl_xor(ts, 2); ts += __shfl_xor(ts, 4);
        if (cg == 0 && 32 * tj + r < V)
            atomicAdd(&d_ws[b * VP + 32 * tj + r], ts);
    }

    // write bf16, both orientations (coalesced u16x4 per thread)
    {
        const int vr = 32 * ti + r;
        if (vr < VP) {
            u16x4 w;
            #pragma unroll
            for (int e = 0; e < 4; ++e) w[e] = f2bf(m[e]);
            *(u16x4*)&smp[vr * UP + 32 * tj + c0] = w;
        }
        if (!diag) {
            const int vr2 = 32 * tj + r;
            if (vr2 < VP) {
                u16x4 w2;
                #pragma unroll
                for (int e = 0; e < 4; ++e) w2[e] = f2bf(Ms[c0 + e][r]);
                *(u16x4*)&smp[vr2 * UP + 32 * ti + c0] = w2;
            }
        }
    }
}

// ============ P2: AttT[n][v][u] = Att[n][u][v] (fp32, zero-padded) + diag ====
__global__ __launch_bounds__(256)
void prep_att(const float* __restrict__ Att,
              float* __restrict__ attT,
              float* __restrict__ adiag)
{
    __shared__ float T[32][33];
    const int n  = blockIdx.x;
    const int ut = blockIdx.y / 7, vt = blockIdx.y % 7;
    const int tid = threadIdx.x;

    for (int idx = tid; idx < 1024; idx += 256) {
        const int rr = idx >> 5, cc = idx & 31;
        const int u = 32 * ut + rr, v = 32 * vt + cc;
        T[rr][cc] = (u < V && v < V) ? Att[(size_t)n * (V * V) + u * V + v] : 0.f;
    }
    __syncthreads();
    for (int idx = tid; idx < 1024; idx += 256) {
        const int r2 = idx >> 5, c2 = idx & 31;
        attT[(size_t)n * (UP * UP) + (32 * vt + r2) * UP + 32 * ut + c2] = T[c2][r2];
    }
    if (ut == vt && tid < 32)
        adiag[n * UP + 32 * vt + tid] = T[tid][tid];
}

// ============ P3: ThT[k][fo][f] = bf16(Theta[k][f][fo]) ============
__global__ __launch_bounds__(256)
void prep_theta(const float* __restrict__ Theta,
                unsigned short* __restrict__ thT)
{
    __shared__ float T[64][65];
    const int k = blockIdx.x, tid = threadIdx.x;
    for (int idx = tid; idx < 4096; idx += 256)
        T[idx >> 6][idx & 63] = Theta[k * 4096 + idx];
    __syncthreads();
    for (int idx = tid; idx < 4096; idx += 256) {
        const int fo = idx >> 6, f = idx & 63;
        thT[k * 4096 + fo * 64 + f] = f2bf(T[f][fo]);
    }
}

// ============ G: MFMA main loop + MFMA Theta epilogue ============
constexpr int XS_S = 68;   // xs stride (bf16)
constexpr int A_S  = 40;   // A-tile stride (bf16)
constexpr int YS_S = 72;   // ys / ThS stride (bf16)

__global__ __launch_bounds__(256, 2)
void cheb_main(const float* __restrict__ x,
               const unsigned short* __restrict__ thT,
               const unsigned short* __restrict__ smin,
               const float* __restrict__ d_ws,
               const float* __restrict__ sdiag,
               const float* __restrict__ attT,
               const float* __restrict__ adiag,
               float* __restrict__ out)
{
    __shared__ __align__(16) char smem[65408];
    unsigned short* xs  = (unsigned short*)smem;            // [224][68] = 30,464 B
    unsigned short* A1  = (unsigned short*)(smem + 30464);  // [208][40] = 16,640 B
    unsigned short* A2  = (unsigned short*)(smem + 47104);  // [208][40] = 16,640 B
    unsigned short* ys  = (unsigned short*)smem;            // [208][72] = 29,952 B (epilogue)
    unsigned short* ThS = (unsigned short*)(smem + 30464);  // [64][72]  =  9,216 B (epilogue)
    float*        cbuf  = (float*)(smem + 63744);           // 832 B
    float*       adbuf  = (float*)(smem + 64576);           // 832 B

    const int tid = threadIdx.x;
    const int b   = blockIdx.x;
    const int n   = b >> 6;
    const float* __restrict__ xp = x + (size_t)b * (V * F);
    const unsigned short* __restrict__ sm = smin + (size_t)b * (VP * UP);
    const float* __restrict__ atp = attT + (size_t)n * (UP * UP);
    float* __restrict__ op = out + (size_t)b * (V * FO);

    // ---- stage x -> bf16 xs[u][f] (zeros for u >= 200) ----
    for (int idx = tid; idx < UP * 16; idx += 256) {
        const int u = idx >> 4, fg = idx & 15;
        u16x4 w; w[0] = 0; w[1] = 0; w[2] = 0; w[3] = 0;
        if (u < V) {
            const float4 v = *(const float4*)&xp[u * F + 4 * fg];
            w[0] = f2bf(v.x); w[1] = f2bf(v.y); w[2] = f2bf(v.z); w[3] = f2bf(v.w);
        }
        *(u16x4*)&xs[u * XS_S + 4 * fg] = w;
    }
    if (tid < VP) {
        cbuf[tid]  = d_ws[b * VP + tid] - 1.0f - sdiag[b * VP + tid];  // c = d-1-S_vv
        adbuf[tid] = adiag[n * UP + tid];
    }

    const int wave = tid >> 6, lane = tid & 63;
    const int q = lane >> 4, ln = lane & 15;
    const int myBase = (wave == 0) ? 0 : (4 + 3 * (wave - 1));
    const int myCnt  = (wave == 0) ? 4 : 3;

    f32x4 acc1[4][4], acc2[4][4];
    #pragma unroll
    for (int i = 0; i < 4; ++i)
        #pragma unroll
        for (int j = 0; j < 4; ++j) {
            acc1[i][j] = (f32x4)0.f; acc2[i][j] = (f32x4)0.f;
        }

    // ---- software-pipelined A-build input prefetch (regs) ----
    u16x8 pf_s[4]; float4 pf_a0[4], pf_a1[4];
    auto load_chunks = [&](int kt) {
        const int u0 = 32 * kt;
        #pragma unroll
        for (int c = 0; c < 4; ++c) {
            const int idx = tid + 256 * c;
            if (idx < VP * 4) {
                const int v = idx >> 2, ch = idx & 3;
                const int u8 = u0 + 8 * ch;
                pf_s[c]  = *(const u16x8*)&sm[v * UP + u8];
                pf_a0[c] = *(const float4*)&atp[v * UP + u8];
                pf_a1[c] = *(const float4*)&atp[v * UP + u8 + 4];
            }
        }
    };
    load_chunks(0);

    // ---- K loop: 7 steps of 32 u's; diagonal (u==v) excluded (fp32 later) ----
    for (int kt = 0; kt < 7; ++kt) {
        const int u0 = 32 * kt;
        __syncthreads();                 // A region free / xs ready (kt=0)
        #pragma unroll
        for (int c = 0; c < 4; ++c) {
            const int idx = tid + 256 * c;
            if (idx < VP * 4) {
                const int v = idx >> 2, ch = idx & 3;
                const int u8 = u0 + 8 * ch;
                const u16x8 s8 = pf_s[c];
                const float att[8] = {pf_a0[c].x, pf_a0[c].y, pf_a0[c].z, pf_a0[c].w,
                                      pf_a1[c].x, pf_a1[c].y, pf_a1[c].z, pf_a1[c].w};
                u16x8 w1, w2;
                #pragma unroll
                for (int jj = 0; jj < 8; ++jj) {
                    const float m = bf2f(s8[jj]);
                    if (u8 + jj == v) { w1[jj] = 0; w2[jj] = 0; }
                    else {
                        w1[jj] = f2bf(-m * att[jj]);
                        w2[jj] = f2bf(2.0f * m * m * att[jj]);
                    }
                }
                *(u16x8*)&A1[v * A_S + 8 * ch] = w1;
                *(u16x8*)&A2[v * A_S + 8 * ch] = w2;
            }
        }
        if (kt < 6) load_chunks(kt + 1);     // latency overlaps barrier+MFMA
        __syncthreads();
        short8 bfr[4];
        #pragma unroll
        for (int ft = 0; ft < 4; ++ft)
            #pragma unroll
            for (int j = 0; j < 8; ++j)
                bfr[ft][j] = (short)xs[(u0 + 8 * q + j) * XS_S + 16 * ft + ln];
        #pragma unroll
        for (int vi = 0; vi < 4; ++vi) {
            if (vi < myCnt) {
                const int row = (myBase + vi) * 16 + ln;
                const short8 af1 = *(const short8*)&A1[row * A_S + 8 * q];
                const short8 af2 = *(const short8*)&A2[row * A_S + 8 * q];
                #pragma unroll
                for (int ft = 0; ft < 4; ++ft) {
                    acc1[vi][ft] = __builtin_amdgcn_mfma_f32_16x16x32_bf16(af1, bfr[ft], acc1[vi][ft], 0, 0, 0);
                    acc2[vi][ft] = __builtin_amdgcn_mfma_f32_16x16x32_bf16(af2, bfr[ft], acc2[vi][ft], 0, 0, 0);
                }
            }
        }
    }

    // ---- epilogue: out-tiles += mfma(ys_k, ThT_k) for k = 1, 2, 0 ----
    f32x4 ot[4][4];
    #pragma unroll
    for (int i = 0; i < 4; ++i)
        #pragma unroll
        for (int j = 0; j < 4; ++j) ot[i][j] = (f32x4)0.f;

    #pragma unroll
    for (int pass = 0; pass < 3; ++pass) {
        const int k = (pass == 0) ? 1 : (pass == 1) ? 2 : 0;
        __syncthreads();   // prev contract / main loop reads done

        if (k == 0) {
            for (int idx = tid; idx < VP * 16; idx += 256) {
                const int v = idx >> 4, fg = idx & 15;
                u16x4 w; w[0] = 0; w[1] = 0; w[2] = 0; w[3] = 0;
                if (v < V) {
                    const float av = adbuf[v];
                    const float4 xv = *(const float4*)&xp[v * F + 4 * fg];
                    w[0] = f2bf(av * xv.x); w[1] = f2bf(av * xv.y);
                    w[2] = f2bf(av * xv.z); w[3] = f2bf(av * xv.w);
                }
                *(u16x4*)&ys[v * YS_S + 4 * fg] = w;
            }
        } else {
            #pragma unroll
            for (int vi = 0; vi < 4; ++vi) {
                if (vi < myCnt) {
                    const int vt = myBase + vi;
                    #pragma unroll
                    for (int ft = 0; ft < 4; ++ft) {
                        const f32x4 a = (k == 1) ? acc1[vi][ft] : acc2[vi][ft];
                        #pragma unroll
                        for (int reg = 0; reg < 4; ++reg) {
                            const int v = vt * 16 + 4 * q + reg;
                            float val = 0.f;
                            if (v < V) {
                                const float cc = cbuf[v];
                                const float dc = ((k == 1) ? cc : (2.0f * cc * cc - 1.0f)) * adbuf[v];
                                val = a[reg] + dc * xp[v * F + 16 * ft + ln];
                            }
                            ys[v * YS_S + 16 * ft + ln] = f2bf(val);
                        }
                    }
                }
            }
        }
        for (int idx = tid; idx < 64 * 8; idx += 256) {
            const int fo = idx >> 3, ch = idx & 7;
            *(u16x8*)&ThS[fo * YS_S + 8 * ch] =
                *(const u16x8*)&thT[k * 4096 + fo * 64 + 8 * ch];
        }
        __syncthreads();
        #pragma unroll
        for (int vi = 0; vi < 4; ++vi) {
            if (vi < myCnt) {
                const int vrow = (myBase + vi) * 16 + ln;
                #pragma unroll
                for (int ks = 0; ks < 2; ++ks) {
                    const short8 af = *(const short8*)&ys[vrow * YS_S + 32 * ks + 8 * q];
                    #pragma unroll
                    for (int fot = 0; fot < 4; ++fot) {
                        const short8 bf = *(const short8*)&ThS[(16 * fot + ln) * YS_S + 32 * ks + 8 * q];
                        ot[vi][fot] = __builtin_amdgcn_mfma_f32_16x16x32_bf16(af, bf, ot[vi][fot], 0, 0, 0);
                    }
                }
            }
        }
    }

    // ---- relu + store (C-layout: row v = 4q+reg, col fo = ln) ----
    #pragma unroll
    for (int vi = 0; vi < 4; ++vi) {
        if (vi < myCnt) {
            const int vt = myBase + vi;
            #pragma unroll
            for (int fot = 0; fot < 4; ++fot) {
                #pragma unroll
                for (int reg = 0; reg < 4; ++reg) {
                    const int v = vt * 16 + 4 * q + reg;
                    if (v < V)
                        op[v * FO + 16 * fot + ln] = fmaxf(ot[vi][fot][reg], 0.f);
                }
            }
        }
    }
}

} // namespace

extern "C" void kernel_launch(void* const* d_in, const int* in_sizes, int n_in,
                              void* d_out, int out_size, void* d_ws, size_t ws_size,
                              hipStream_t stream) {
    const float* x     = (const float*)d_in[0];
    const float* Att   = (const float*)d_in[1];
    const float* S     = (const float*)d_in[2];
    const float* Theta = (const float*)d_in[3];
    float* out         = (float*)d_out;

    char* ws = (char*)d_ws;
    unsigned short* smin = (unsigned short*)(ws + WS_SMIN);
    float* d_sum = (float*)(ws + WS_D);
    float* sdiag = (float*)(ws + WS_SDIAG);
    float* attT  = (float*)(ws + WS_ATTT);
    float* adiag = (float*)(ws + WS_ADIAG);
    unsigned short* thT = (unsigned short*)(ws + WS_THT);

    // d accumulates via atomicAdd -> must start at 0 every call
    hipMemsetAsync(d_sum, 0, (size_t)NT * VP * sizeof(float), stream);

    hipLaunchKernelGGL(prep_smin,  dim3(NT, 28), dim3(256), 0, stream, S, smin, d_sum, sdiag);
    hipLaunchKernelGGL(prep_att,   dim3(8, 49),  dim3(256), 0, stream, Att, attT, adiag);
    hipLaunchKernelGGL(prep_theta, dim3(3),      dim3(256), 0, stream, Theta, thT);
    hipLaunchKernelGGL(cheb_main,  dim3(NT),     dim3(256), 0, stream,
                       x, thT, smin, d_sum, sdiag, attT, adiag, out);
}